// Round 5
// baseline (5635.877 us; speedup 1.0000x reference)
//
#include <hip/hip_runtime.h>

#define T_N 4096
#define B_N 64
#define I_N 128
#define H_N 128
#define BH  (B_N * H_N)
#define NB  4          // batch elements per scan block

// ---------------------------------------------------------------------------
// Phase 1: xp[t,b,:] = x[t,b,:] @ W_ih^T + b_ih -> written into out[0..T*B*H)
// (phase 2 reads it and overwrites with h_t in place). Unchanged from R2-R4.
// ---------------------------------------------------------------------------
__global__ __launch_bounds__(256) void xproj_kernel(
    const float* __restrict__ x, const float* __restrict__ Wih,
    const float* __restrict__ bih, float* __restrict__ xp)
{
    __shared__ float wt[I_N][H_N];   // wt[k][j] = Wih[j][k], 64 KB
    const int tid = threadIdx.x;

    {
        const float4* w4 = (const float4*)Wih;
        #pragma unroll
        for (int it = 0; it < 16; ++it) {
            int i = tid * 16 + it;          // 0..4095 float4s
            float4 v = w4[i];
            int r = i >> 5;                 // W row j
            int k = (i & 31) << 2;          // k base
            wt[k + 0][r] = v.x;
            wt[k + 1][r] = v.y;
            wt[k + 2][r] = v.z;
            wt[k + 3][r] = v.w;
        }
    }
    __syncthreads();

    const int  tx   = tid & 15;
    const int  ty   = tid >> 4;
    const long row0 = (long)blockIdx.x * 128;
    const float* xbase = x + (row0 + ty * 8) * I_N;

    float acc[8][8];
    #pragma unroll
    for (int r = 0; r < 8; ++r)
        #pragma unroll
        for (int c = 0; c < 8; ++c) acc[r][c] = 0.0f;

    #pragma unroll 2
    for (int k4 = 0; k4 < I_N / 4; ++k4) {
        float4 xv[8];
        #pragma unroll
        for (int r = 0; r < 8; ++r)
            xv[r] = *(const float4*)(xbase + r * I_N + k4 * 4);

        #pragma unroll
        for (int kk = 0; kk < 4; ++kk) {
            int k = k4 * 4 + kk;
            float4 w0 = *(const float4*)&wt[k][tx * 4];
            float4 w1 = *(const float4*)&wt[k][64 + tx * 4];
            #pragma unroll
            for (int r = 0; r < 8; ++r) {
                float xk = (kk == 0) ? xv[r].x : (kk == 1) ? xv[r].y
                         : (kk == 2) ? xv[r].z : xv[r].w;
                acc[r][0] = fmaf(xk, w0.x, acc[r][0]);
                acc[r][1] = fmaf(xk, w0.y, acc[r][1]);
                acc[r][2] = fmaf(xk, w0.z, acc[r][2]);
                acc[r][3] = fmaf(xk, w0.w, acc[r][3]);
                acc[r][4] = fmaf(xk, w1.x, acc[r][4]);
                acc[r][5] = fmaf(xk, w1.y, acc[r][5]);
                acc[r][6] = fmaf(xk, w1.z, acc[r][6]);
                acc[r][7] = fmaf(xk, w1.w, acc[r][7]);
            }
        }
    }

    float4 b0 = *(const float4*)(bih + tx * 4);
    float4 b1 = *(const float4*)(bih + 64 + tx * 4);
    #pragma unroll
    for (int r = 0; r < 8; ++r) {
        long row = row0 + ty * 8 + r;
        float4 o0, o1;
        o0.x = acc[r][0] + b0.x;  o0.y = acc[r][1] + b0.y;
        o0.z = acc[r][2] + b0.z;  o0.w = acc[r][3] + b0.w;
        o1.x = acc[r][4] + b1.x;  o1.y = acc[r][5] + b1.y;
        o1.z = acc[r][6] + b1.z;  o1.w = acc[r][7] + b1.w;
        *(float4*)(xp + row * H_N + tx * 4)      = o0;
        *(float4*)(xp + row * H_N + 64 + tx * 4) = o1;
    }
}

// ---------------------------------------------------------------------------
// Phase 2: sequential scan. R5: NB=4 independent batch chains per block
// (16 blocks). Same per-batch decomposition as R3/R4 (lane l: p =
// (l&3)|((l>>1)&4) k-slice, jt = bits{2,4,5}+8*wave, DPP xor1/xor2/xor8
// reduce, padded LDS chunks, raw s_barrier + lgkmcnt(0) only). The 4
// chains share W fragments and interleave to fill latency bubbles; one
// barrier per step hands off all 4 states.
// ---------------------------------------------------------------------------
__device__ __forceinline__ float tanh_pade(float x) {
    float u = x * x;
    float n = fmaf(u, u + 105.0f, 945.0f);              // u^2 + 105u + 945
    float d = fmaf(u, fmaf(15.0f, u, 420.0f), 945.0f);  // 15u^2 + 420u + 945
    float t = x * n * __builtin_amdgcn_rcpf(d);
    return fminf(1.0f, fmaxf(-1.0f, t));                // v_med3_f32
}

#define DPP_XOR1 0xB1   // quad_perm [1,0,3,2]
#define DPP_XOR2 0x4E   // quad_perm [2,3,0,1]
#define DPP_XOR8 0x128  // row_ror:8  (== xor8 within a 16-lane row)

__device__ __forceinline__ float dpp_add(float v, const int ctrl) {
    int s = __float_as_int(v);
    int r;
    switch (ctrl) {  // ctrl must be compile-time; switch keeps it literal
        case DPP_XOR1: r = __builtin_amdgcn_update_dpp(0, s, DPP_XOR1, 0xF, 0xF, true); break;
        case DPP_XOR2: r = __builtin_amdgcn_update_dpp(0, s, DPP_XOR2, 0xF, 0xF, true); break;
        default:       r = __builtin_amdgcn_update_dpp(0, s, DPP_XOR8, 0xF, 0xF, true); break;
    }
    return v + __int_as_float(r);
}

#define DOT4(W4, H4)                                                          \
    fmaf((W4).x, (H4).x, fmaf((W4).y, (H4).y,                                 \
    fmaf((W4).z, (H4).z, (W4).w * (H4).w)))

__global__ __launch_bounds__(256, 1) void scan_kernel(
    const float* __restrict__ Whh, const float* __restrict__ bhh,
    const float* __restrict__ h0, float* __restrict__ out)
{
    const int tid  = threadIdx.x;
    const int b0   = blockIdx.x * NB;
    const int lane = tid & 63;
    const int wv   = tid >> 6;
    const int p    = (lane & 3) | ((lane >> 1) & 4);          // 0..7
    const int jt   = (((lane >> 2) & 1) | ((lane >> 4) << 1)) + wv * 8;  // 0..31
    __shared__ float hbuf[2][NB][8][20];  // [buf][batch][chunk][16 + 4 pad]

    // W fragment (shared by all NB chains): w[j][c] = Whh[4jt+j][16p+4c ..+4)
    float4 w[4][4];
    #pragma unroll
    for (int j = 0; j < 4; ++j)
        #pragma unroll
        for (int c = 0; c < 4; ++c)
            w[j][c] = *(const float4*)(Whh + (4 * jt + j) * H_N + 16 * p + 4 * c);

    const float4 bh4 = *(const float4*)(bhh + 4 * jt);

    if (tid < H_N) {
        #pragma unroll
        for (int bt = 0; bt < NB; ++bt)
            hbuf[0][bt][tid >> 4][tid & 15] = h0[(b0 + bt) * H_N + tid];
    }

    const float* xq[NB];
    float*       oq[NB];
    #pragma unroll
    for (int bt = 0; bt < NB; ++bt) {
        xq[bt] = out + (b0 + bt) * H_N + 4 * jt;
        oq[bt] = out + (b0 + bt) * H_N + 4 * jt;
    }

    float4 xv[4][NB];   // [prefetch-slot][batch]
    #pragma unroll
    for (int d = 0; d < 4; ++d)
        #pragma unroll
        for (int bt = 0; bt < NB; ++bt)
            xv[d][bt] = *(const float4*)(xq[bt] + (size_t)d * BH);

    __syncthreads();

#define RNN_STEP(T0, D, CUR) do {                                             \
        float4 hv[NB][4];                                                     \
        _Pragma("unroll")                                                     \
        for (int bt = 0; bt < NB; ++bt) {                                     \
            hv[bt][0] = *(const float4*)&hbuf[CUR][bt][p][0];                 \
            hv[bt][1] = *(const float4*)&hbuf[CUR][bt][p][4];                 \
            hv[bt][2] = *(const float4*)&hbuf[CUR][bt][p][8];                 \
            hv[bt][3] = *(const float4*)&hbuf[CUR][bt][p][12];                \
        }                                                                     \
        float s[NB][4];                                                       \
        _Pragma("unroll")                                                     \
        for (int bt = 0; bt < NB; ++bt) {                                     \
            s[bt][0] = (DOT4(w[0][0], hv[bt][0]) + DOT4(w[0][1], hv[bt][1]))  \
                     + (DOT4(w[0][2], hv[bt][2]) + DOT4(w[0][3], hv[bt][3])); \
            s[bt][1] = (DOT4(w[1][0], hv[bt][0]) + DOT4(w[1][1], hv[bt][1]))  \
                     + (DOT4(w[1][2], hv[bt][2]) + DOT4(w[1][3], hv[bt][3])); \
            s[bt][2] = (DOT4(w[2][0], hv[bt][0]) + DOT4(w[2][1], hv[bt][1]))  \
                     + (DOT4(w[2][2], hv[bt][2]) + DOT4(w[2][3], hv[bt][3])); \
            s[bt][3] = (DOT4(w[3][0], hv[bt][0]) + DOT4(w[3][1], hv[bt][1]))  \
                     + (DOT4(w[3][2], hv[bt][2]) + DOT4(w[3][3], hv[bt][3])); \
        }                                                                     \
        _Pragma("unroll")                                                     \
        for (int bt = 0; bt < NB; ++bt) {                                     \
            s[bt][0] = dpp_add(s[bt][0], DPP_XOR1);                           \
            s[bt][1] = dpp_add(s[bt][1], DPP_XOR1);                           \
            s[bt][2] = dpp_add(s[bt][2], DPP_XOR1);                           \
            s[bt][3] = dpp_add(s[bt][3], DPP_XOR1);                           \
            s[bt][0] = dpp_add(s[bt][0], DPP_XOR2);                           \
            s[bt][1] = dpp_add(s[bt][1], DPP_XOR2);                           \
            s[bt][2] = dpp_add(s[bt][2], DPP_XOR2);                           \
            s[bt][3] = dpp_add(s[bt][3], DPP_XOR2);                           \
            s[bt][0] = dpp_add(s[bt][0], DPP_XOR8);                           \
            s[bt][1] = dpp_add(s[bt][1], DPP_XOR8);                           \
            s[bt][2] = dpp_add(s[bt][2], DPP_XOR8);                           \
            s[bt][3] = dpp_add(s[bt][3], DPP_XOR8);                           \
        }                                                                     \
        float4 h4[NB];                                                        \
        _Pragma("unroll")                                                     \
        for (int bt = 0; bt < NB; ++bt) {                                     \
            h4[bt].x = tanh_pade(s[bt][0] + xv[D][bt].x + bh4.x);             \
            h4[bt].y = tanh_pade(s[bt][1] + xv[D][bt].y + bh4.y);             \
            h4[bt].z = tanh_pade(s[bt][2] + xv[D][bt].z + bh4.z);             \
            h4[bt].w = tanh_pade(s[bt][3] + xv[D][bt].w + bh4.w);             \
        }                                                                     \
        if (p == 0) {                                                         \
            _Pragma("unroll")                                                 \
            for (int bt = 0; bt < NB; ++bt)                                   \
                *(float4*)&hbuf[(CUR) ^ 1][bt][jt >> 2][(jt & 3) << 2] = h4[bt]; \
        }                                                                     \
        asm volatile("s_waitcnt lgkmcnt(0)" ::: "memory");                    \
        __builtin_amdgcn_s_barrier();                                         \
        if (p == 0) {                                                         \
            _Pragma("unroll")                                                 \
            for (int bt = 0; bt < NB; ++bt) {                                 \
                *(float4*)(oq[bt] + (size_t)(T0) * BH) = h4[bt];              \
                if ((T0) == T_N - 1)                                          \
                    *(float4*)(oq[bt] + (size_t)T_N * BH) = h4[bt];           \
            }                                                                 \
        }                                                                     \
        asm volatile("" ::: "memory");                                        \
    } while (0)

#define PREFETCH(D, TNEXT) do {                                               \
        if ((TNEXT) < T_N) {                                                  \
            _Pragma("unroll")                                                 \
            for (int bt = 0; bt < NB; ++bt)                                   \
                xv[D][bt] = *(const float4*)(xq[bt] + (size_t)(TNEXT) * BH);  \
        }                                                                     \
    } while (0)

    for (int t = 0; t < T_N; t += 4) {
        RNN_STEP(t + 0, 0, 0);
        PREFETCH(0, t + 4);
        RNN_STEP(t + 1, 1, 1);
        PREFETCH(1, t + 5);
        RNN_STEP(t + 2, 2, 0);
        PREFETCH(2, t + 6);
        RNN_STEP(t + 3, 3, 1);
        PREFETCH(3, t + 7);
    }
#undef RNN_STEP
#undef PREFETCH
}

extern "C" void kernel_launch(void* const* d_in, const int* in_sizes, int n_in,
                              void* d_out, int out_size, void* d_ws, size_t ws_size,
                              hipStream_t stream) {
    const float* x   = (const float*)d_in[0];
    const float* h0  = (const float*)d_in[1];
    const float* Wih = (const float*)d_in[2];
    const float* Whh = (const float*)d_in[3];
    const float* bih = (const float*)d_in[4];
    const float* bhh = (const float*)d_in[5];
    float* out = (float*)d_out;

    xproj_kernel<<<dim3((T_N * B_N) / 128), 256, 0, stream>>>(x, Wih, bih, out);
    scan_kernel<<<dim3(B_N / NB), 256, 0, stream>>>(Whh, bhh, h0, out);
}

// Round 6
// 1969.419 us; speedup vs baseline: 2.8617x; 2.8617x over previous
//
#include <hip/hip_runtime.h>

#define T_N 4096
#define B_N 64
#define I_N 128
#define H_N 128
#define BH  (B_N * H_N)

// ---------------------------------------------------------------------------
// Phase 1: xp[t,b,:] = x[t,b,:] @ W_ih^T + b_ih -> written into out[0..T*B*H)
// (phase 2 reads it and overwrites with h_t in place). Unchanged from R2-R5.
// ---------------------------------------------------------------------------
__global__ __launch_bounds__(256) void xproj_kernel(
    const float* __restrict__ x, const float* __restrict__ Wih,
    const float* __restrict__ bih, float* __restrict__ xp)
{
    __shared__ float wt[I_N][H_N];   // wt[k][j] = Wih[j][k], 64 KB
    const int tid = threadIdx.x;

    {
        const float4* w4 = (const float4*)Wih;
        #pragma unroll
        for (int it = 0; it < 16; ++it) {
            int i = tid * 16 + it;          // 0..4095 float4s
            float4 v = w4[i];
            int r = i >> 5;                 // W row j
            int k = (i & 31) << 2;          // k base
            wt[k + 0][r] = v.x;
            wt[k + 1][r] = v.y;
            wt[k + 2][r] = v.z;
            wt[k + 3][r] = v.w;
        }
    }
    __syncthreads();

    const int  tx   = tid & 15;
    const int  ty   = tid >> 4;
    const long row0 = (long)blockIdx.x * 128;
    const float* xbase = x + (row0 + ty * 8) * I_N;

    float acc[8][8];
    #pragma unroll
    for (int r = 0; r < 8; ++r)
        #pragma unroll
        for (int c = 0; c < 8; ++c) acc[r][c] = 0.0f;

    #pragma unroll 2
    for (int k4 = 0; k4 < I_N / 4; ++k4) {
        float4 xv[8];
        #pragma unroll
        for (int r = 0; r < 8; ++r)
            xv[r] = *(const float4*)(xbase + r * I_N + k4 * 4);

        #pragma unroll
        for (int kk = 0; kk < 4; ++kk) {
            int k = k4 * 4 + kk;
            float4 w0 = *(const float4*)&wt[k][tx * 4];
            float4 w1 = *(const float4*)&wt[k][64 + tx * 4];
            #pragma unroll
            for (int r = 0; r < 8; ++r) {
                float xk = (kk == 0) ? xv[r].x : (kk == 1) ? xv[r].y
                         : (kk == 2) ? xv[r].z : xv[r].w;
                acc[r][0] = fmaf(xk, w0.x, acc[r][0]);
                acc[r][1] = fmaf(xk, w0.y, acc[r][1]);
                acc[r][2] = fmaf(xk, w0.z, acc[r][2]);
                acc[r][3] = fmaf(xk, w0.w, acc[r][3]);
                acc[r][4] = fmaf(xk, w1.x, acc[r][4]);
                acc[r][5] = fmaf(xk, w1.y, acc[r][5]);
                acc[r][6] = fmaf(xk, w1.z, acc[r][6]);
                acc[r][7] = fmaf(xk, w1.w, acc[r][7]);
            }
        }
    }

    float4 b0 = *(const float4*)(bih + tx * 4);
    float4 b1 = *(const float4*)(bih + 64 + tx * 4);
    #pragma unroll
    for (int r = 0; r < 8; ++r) {
        long row = row0 + ty * 8 + r;
        float4 o0, o1;
        o0.x = acc[r][0] + b0.x;  o0.y = acc[r][1] + b0.y;
        o0.z = acc[r][2] + b0.z;  o0.w = acc[r][3] + b0.w;
        o1.x = acc[r][4] + b1.x;  o1.y = acc[r][5] + b1.y;
        o1.z = acc[r][6] + b1.z;  o1.w = acc[r][7] + b1.w;
        *(float4*)(xp + row * H_N + tx * 4)      = o0;
        *(float4*)(xp + row * H_N + 64 + tx * 4) = o1;
    }
}

// ---------------------------------------------------------------------------
// Phase 2: scan, one block per batch element (64 blocks), now 512 threads =
// 8 waves = 2 waves/SIMD so one wave's issue fills the other's barrier/LDS
// stall (R4's 850-cyc unhidden serial region).
// Thread (p = lane&15 -> k-slice [8p,8p+8), jg = (lane>>4)+4*wave -> outputs
// j = 4jg..4jg+3). Per thread: 32 FMA, 32B LDS read. 16-wide k-reduce = 4 DPP
// row_ror rounds (within the 16-lane row). hbuf padded [16][12]: 16B-aligned
// b128, 2-way max bank aliasing (free). ds_write right after tanh; prefetch
// and global store issued before the lgkm drain; raw s_barrier.
// ---------------------------------------------------------------------------
__device__ __forceinline__ float tanh_pade(float x) {
    float u = x * x;
    float n = fmaf(u, u + 105.0f, 945.0f);              // u^2 + 105u + 945
    float d = fmaf(u, fmaf(15.0f, u, 420.0f), 945.0f);  // 15u^2 + 420u + 945
    float t = x * n * __builtin_amdgcn_rcpf(d);
    return fminf(1.0f, fmaxf(-1.0f, t));                // v_med3_f32
}

#define ROR1 0x121
#define ROR2 0x122
#define ROR4 0x124
#define ROR8 0x128

__device__ __forceinline__ float ror_add(float v, const int ctrl) {
    int s = __float_as_int(v);
    int r;
    switch (ctrl) {  // ctrl must be a literal
        case ROR1: r = __builtin_amdgcn_update_dpp(0, s, ROR1, 0xF, 0xF, true); break;
        case ROR2: r = __builtin_amdgcn_update_dpp(0, s, ROR2, 0xF, 0xF, true); break;
        case ROR4: r = __builtin_amdgcn_update_dpp(0, s, ROR4, 0xF, 0xF, true); break;
        default:   r = __builtin_amdgcn_update_dpp(0, s, ROR8, 0xF, 0xF, true); break;
    }
    return v + __int_as_float(r);
}

#define DOT4(W4, H4)                                                          \
    fmaf((W4).x, (H4).x, fmaf((W4).y, (H4).y,                                 \
    fmaf((W4).z, (H4).z, (W4).w * (H4).w)))

__global__ __launch_bounds__(512, 1) void scan_kernel(
    const float* __restrict__ Whh, const float* __restrict__ bhh,
    const float* __restrict__ h0, float* __restrict__ out)
{
    const int tid  = threadIdx.x;
    const int b    = blockIdx.x;
    const int lane = tid & 63;
    const int wv   = tid >> 6;                 // 0..7
    const int p    = lane & 15;                // k-slice [8p, 8p+8)
    const int jg   = (lane >> 4) + 4 * wv;     // 0..31 ; j = 4*jg + {0..3}
    __shared__ float hbuf[2][16][12];          // [buf][k-chunk p][8 + 4 pad]

    // W fragment: w4[j][c] = Whh[4jg+j][8p + 4c .. +4)
    float4 w4[4][2];
    #pragma unroll
    for (int j = 0; j < 4; ++j)
        #pragma unroll
        for (int c = 0; c < 2; ++c)
            w4[j][c] = *(const float4*)(Whh + (4 * jg + j) * H_N + 8 * p + 4 * c);

    const float4 bh4 = *(const float4*)(bhh + 4 * jg);

    if (tid < H_N) hbuf[0][tid >> 3][tid & 7] = h0[b * H_N + tid];

    const float* xq = out + b * H_N + 4 * jg;   // xp (t,b,4jg..) at xq + t*BH
    float*       oq = out + b * H_N + 4 * jg;

    float4 xv[4];
    #pragma unroll
    for (int d = 0; d < 4; ++d)
        xv[d] = *(const float4*)(xq + (size_t)d * BH);

    __syncthreads();

#define RNN_STEP(T0, D, CUR) do {                                             \
        float4 hv0 = *(const float4*)&hbuf[CUR][p][0];                        \
        float4 hv1 = *(const float4*)&hbuf[CUR][p][4];                        \
        float s0 = DOT4(w4[0][0], hv0) + DOT4(w4[0][1], hv1);                 \
        float s1 = DOT4(w4[1][0], hv0) + DOT4(w4[1][1], hv1);                 \
        float s2 = DOT4(w4[2][0], hv0) + DOT4(w4[2][1], hv1);                 \
        float s3 = DOT4(w4[3][0], hv0) + DOT4(w4[3][1], hv1);                 \
        s0 = ror_add(s0, ROR1); s1 = ror_add(s1, ROR1);                       \
        s2 = ror_add(s2, ROR1); s3 = ror_add(s3, ROR1);                       \
        s0 = ror_add(s0, ROR2); s1 = ror_add(s1, ROR2);                       \
        s2 = ror_add(s2, ROR2); s3 = ror_add(s3, ROR2);                       \
        s0 = ror_add(s0, ROR4); s1 = ror_add(s1, ROR4);                       \
        s2 = ror_add(s2, ROR4); s3 = ror_add(s3, ROR4);                       \
        s0 = ror_add(s0, ROR8); s1 = ror_add(s1, ROR8);                       \
        s2 = ror_add(s2, ROR8); s3 = ror_add(s3, ROR8);                       \
        float4 h4;                                                            \
        h4.x = tanh_pade(s0 + xv[D].x + bh4.x);                               \
        h4.y = tanh_pade(s1 + xv[D].y + bh4.y);                               \
        h4.z = tanh_pade(s2 + xv[D].z + bh4.z);                               \
        h4.w = tanh_pade(s3 + xv[D].w + bh4.w);                               \
        if (p == 0)                                                           \
            *(float4*)&hbuf[(CUR) ^ 1][jg >> 1][(jg & 1) << 2] = h4;          \
        if ((T0) + 4 < T_N)                                                   \
            xv[D] = *(const float4*)(xq + (size_t)((T0) + 4) * BH);           \
        if (p == 0) {                                                         \
            *(float4*)(oq + (size_t)(T0) * BH) = h4;                          \
            if ((T0) == T_N - 1) *(float4*)(oq + (size_t)T_N * BH) = h4;      \
        }                                                                     \
        asm volatile("s_waitcnt lgkmcnt(0)" ::: "memory");                    \
        __builtin_amdgcn_s_barrier();                                         \
        asm volatile("" ::: "memory");                                        \
    } while (0)

    for (int t = 0; t < T_N; t += 4) {
        RNN_STEP(t + 0, 0, 0);
        RNN_STEP(t + 1, 1, 1);
        RNN_STEP(t + 2, 2, 0);
        RNN_STEP(t + 3, 3, 1);
    }
#undef RNN_STEP
}

extern "C" void kernel_launch(void* const* d_in, const int* in_sizes, int n_in,
                              void* d_out, int out_size, void* d_ws, size_t ws_size,
                              hipStream_t stream) {
    const float* x   = (const float*)d_in[0];
    const float* h0  = (const float*)d_in[1];
    const float* Wih = (const float*)d_in[2];
    const float* Whh = (const float*)d_in[3];
    const float* bih = (const float*)d_in[4];
    const float* bhh = (const float*)d_in[5];
    float* out = (float*)d_out;

    xproj_kernel<<<dim3((T_N * B_N) / 128), 256, 0, stream>>>(x, Wih, bih, out);
    scan_kernel<<<dim3(B_N), 512, 0, stream>>>(Whh, bhh, h0, out);
}